// Round 12
// baseline (201.637 us; speedup 1.0000x reference)
//
#include <hip/hip_runtime.h>

typedef __attribute__((ext_vector_type(8))) _Float16 h8;
typedef __attribute__((ext_vector_type(4))) _Float16 h4;
typedef __attribute__((ext_vector_type(4))) float f4;
typedef __attribute__((ext_vector_type(16))) float f16x;
typedef __attribute__((ext_vector_type(4))) unsigned u4;

#define MFMA16(a,b,c) __builtin_amdgcn_mfma_f32_16x16x32_f16(a,b,c,0,0,0)
#define MFMA32(a,b,c) __builtin_amdgcn_mfma_f32_32x32x16_f16(a,b,c,0,0,0)

// async global->LDS, 16B per lane; LDS dest = wave-uniform base + lane*16
__device__ inline void gload16(const void* g, void* l) {
    __builtin_amdgcn_global_load_lds(
        (const __attribute__((address_space(1))) void*)g,
        (__attribute__((address_space(3))) void*)l, 16, 0, 0);
}

// partner-half (lane ^ 32) value, semantics-guaranteed
__device__ inline float swap_half(float x) { return __shfl_xor(x, 32, 64); }

// ---------------- fp32 -> f16 elementwise (vectorized) ----------------
__global__ __launch_bounds__(256) void k_f32_to_f16(const float* __restrict__ in,
                                                    _Float16* __restrict__ out, int n4) {
    int i = blockIdx.x * 256 + threadIdx.x;
    if (i < n4) {
        float4 v = ((const float4*)in)[i];
        h4 h;
        h[0] = (_Float16)v.x; h[1] = (_Float16)v.y;
        h[2] = (_Float16)v.z; h[3] = (_Float16)v.w;
        ((h4*)out)[i] = h;
    }
}

// ---------------- fp32 (K,N) -> f16 (N,K) tiled transpose ----------------
__global__ __launch_bounds__(256) void k_transpose_f16(const float* __restrict__ W,
                                                       _Float16* __restrict__ Wt,
                                                       int K, int N) {
    __shared__ float tile[64 * 68];
    const int k0 = blockIdx.x * 64, n0 = blockIdx.y * 64;
    const int t = threadIdx.x;
    const int tr = t >> 4;
    const int tc = t & 15;
#pragma unroll
    for (int i = 0; i < 4; ++i) {
        int r = tr + i * 16;
        float4 v = *(const float4*)(W + (size_t)(k0 + r) * N + n0 + tc * 4);
        *(float4*)(&tile[r * 68 + tc * 4]) = v;
    }
    __syncthreads();
#pragma unroll
    for (int i = 0; i < 4; ++i) {
        int nl = tr + i * 16;
        h4 hv;
#pragma unroll
        for (int j = 0; j < 4; ++j)
            hv[j] = (_Float16)tile[(tc * 4 + j) * 68 + nl];
        *(h4*)(Wt + (size_t)(n0 + nl) * K + k0 + tc * 4) = hv;
    }
}

// ======== 256x128 deep-pipelined GEMM: 3 LDS slots, T4 counted vmcnt(6) ========
// 8 waves (2Mx4N, per-wave 128x32), BK=64, 16x16x32 MFMA.
// Iteration tau: 4 phases; phases 0/1/2 stage chunks of tile tau+2 into slot
// (tau+2)%3 (A rows 0-127, A rows 128-255, B); phase 3 waits vmcnt(6) == exactly
// tile tau+2's outstanding loads => tile tau+1 resident, tau+2's loads stay in
// flight across the barrier (never drain to 0 in steady state). Cover for each
// tile's loads ~= one full iteration. Slot write-after-read safe: slot (tau+2)%3's
// readers finished at iteration tau-1's trailing barrier.
// T2 swizzle (verified r11, 0 bank conflicts): LDS (row,seg) holds global seg
// seg^(row&7); pre-swizzled stage source col + swizzled frag-read seg.
// MODE 0: scatter Q/K (B,H,T,64), V^T (B,H,64,T); Q pre-scaled 0.125*log2(e).
// MODE 1: f32 out.
template <int MODE>
__global__ __launch_bounds__(512, 2) void k_gemm3(const _Float16* __restrict__ A,
                                                  const _Float16* __restrict__ Bt,
                                                  const float* __restrict__ bias,
                                                  _Float16* __restrict__ oQ,
                                                  _Float16* __restrict__ oK,
                                                  _Float16* __restrict__ oV,
                                                  float* __restrict__ oF,
                                                  int K, int N, int nbn) {
    __shared__ _Float16 As[3][256 * 64];
    __shared__ _Float16 Bs[3][128 * 64];
    const int nwg = gridDim.x;
    const int q8 = nwg >> 3;               // nwg % 8 == 0
    const int wg = (blockIdx.x & 7) * q8 + (blockIdx.x >> 3);   // XCD-chunked, bijective
    const int bm = (wg / nbn) * 256, bn = (wg % nbn) * 128;
    const int tid = threadIdx.x, lane = tid & 63, wv = tid >> 6;
    const int wm = wv >> 2, wn = wv & 3;   // per-wave out: 128 x 32
    const int l15 = lane & 15, l4 = lane >> 4;
    const int sr8 = lane >> 3;             // stage row-in-octet
    const int sseg = ((lane & 7) ^ sr8) * 8;   // T2 pre-swizzled source col
    const _Float16* Ag = A + (size_t)(bm + wv * 8 + sr8) * K + sseg;
    const _Float16* Bg = Bt + (size_t)(bn + wv * 8 + sr8) * K + sseg;
    f4 acc[8][2] = {};

    const int NT = K >> 6;

    auto stageA01 = [&](size_t ko, int s) {
        gload16(Ag + ko, &As[s][(wv * 8) * 64]);
        gload16(Ag + (size_t)64 * K + ko, &As[s][(64 + wv * 8) * 64]);
    };
    auto stageA23 = [&](size_t ko, int s) {
        gload16(Ag + (size_t)128 * K + ko, &As[s][(128 + wv * 8) * 64]);
        gload16(Ag + (size_t)192 * K + ko, &As[s][(192 + wv * 8) * 64]);
    };
    auto stageB = [&](size_t ko, int s) {
        gload16(Bg + ko, &Bs[s][(wv * 8) * 64]);
        gload16(Bg + (size_t)64 * K + ko, &Bs[s][(64 + wv * 8) * 64]);
    };

    // prologue: tiles 0,1 -> slots 0,1 (12 loads in flight)
    stageA01(0, 0); stageA23(0, 0); stageB(0, 0);
    stageA01(64, 1); stageA23(64, 1); stageB(64, 1);
    asm volatile("s_waitcnt vmcnt(6)" ::: "memory");   // tile 0 resident
    __builtin_amdgcn_s_barrier();

    int cs = 0;                            // slot of tile tau
    for (int tau = 0; tau < NT; ++tau) {
        const int s2 = cs + 2 >= 3 ? cs - 1 : cs + 2;  // slot of tile tau+2
        const bool pre2 = (tau + 2 < NT);
        const size_t ko2 = (size_t)(tau + 2) << 6;

        // B-frags for this tile (slot resident since last iteration's q3 wait)
        h8 bf[2][2];
#pragma unroll
        for (int nf = 0; nf < 2; ++nf)
#pragma unroll
            for (int ks = 0; ks < 2; ++ks) {
                const int row = wn * 32 + nf * 16 + l15;
                const int seg = (ks * 4 + l4) ^ (l15 & 7);
                bf[nf][ks] = *(const h8*)(&Bs[cs][row * 64 + seg * 8]);
            }

#pragma unroll
        for (int q = 0; q < 4; ++q) {
            h8 af[2][2];
#pragma unroll
            for (int mi = 0; mi < 2; ++mi)
#pragma unroll
                for (int ks = 0; ks < 2; ++ks) {
                    const int row = wm * 128 + (2 * q + mi) * 16 + l15;
                    const int seg = (ks * 4 + l4) ^ (l15 & 7);
                    af[mi][ks] = *(const h8*)(&As[cs][row * 64 + seg * 8]);
                }
            if (q == 0) { if (pre2) stageA01(ko2, s2); }
            else if (q == 1) { if (pre2) stageA23(ko2, s2); }
            else if (q == 2) { if (pre2) stageB(ko2, s2); }
            else {
                // T4: counted drain — tile tau+1 resident, tau+2's 6 loads stay in flight
                if (pre2)              asm volatile("s_waitcnt vmcnt(6)" ::: "memory");
                else if (tau + 1 < NT) asm volatile("s_waitcnt vmcnt(0)" ::: "memory");
            }
            __builtin_amdgcn_s_barrier();
            __builtin_amdgcn_s_setprio(1);
#pragma unroll
            for (int mi = 0; mi < 2; ++mi)
#pragma unroll
                for (int nf = 0; nf < 2; ++nf)
#pragma unroll
                    for (int ks = 0; ks < 2; ++ks)
                        acc[2 * q + mi][nf] = MFMA16(af[mi][ks], bf[nf][ks], acc[2 * q + mi][nf]);
            __builtin_amdgcn_s_setprio(0);
            __builtin_amdgcn_s_barrier();
        }
        cs = cs + 1 == 3 ? 0 : cs + 1;
    }

    // epilogue
#pragma unroll
    for (int mf = 0; mf < 8; ++mf) {
#pragma unroll
        for (int nf = 0; nf < 2; ++nf) {
            const int col = bn + wn * 32 + nf * 16 + l15;
            const float bv = bias[col];
            const int rb = bm + wm * 128 + mf * 16 + l4 * 4;
            if (MODE == 0) {
                const int which = col >> 10;
                const int hh = (col & 1023) >> 6, dd = col & 63;
                if (which == 2) {
                    const int b = rb >> 11, tq = rb & 2047;
                    h4 pv;
#pragma unroll
                    for (int i = 0; i < 4; ++i) pv[i] = (_Float16)(acc[mf][nf][i] + bv);
                    *(h4*)(oV + ((size_t)(b * 16 + hh) * 64 + dd) * 2048 + tq) = pv;
                } else {
                    _Float16* dst = which == 0 ? oQ : oK;
                    const float scl = which == 0 ? 0.18033688011112042f : 1.0f; // 0.125*log2(e)
#pragma unroll
                    for (int i = 0; i < 4; ++i) {
                        const int row = rb + i;
                        const int b = row >> 11, tq = row & 2047;
                        dst[(((size_t)b * 16 + hh) * 2048 + tq) * 64 + dd] =
                            (_Float16)((acc[mf][nf][i] + bv) * scl);
                    }
                }
            } else {
#pragma unroll
                for (int i = 0; i < 4; ++i)
                    oF[(size_t)(rb + i) * N + col] = acc[mf][nf][i] + bv;
            }
        }
    }
}

// ---------------- causal flash attention: 4 waves x 32 q-rows, shared 64-key K/V tile ----------------
#define SWZI(row, cb) ((((row) << 7) + ((cb) ^ ((((row) & 7) << 4)))) >> 1)

__global__ __launch_bounds__(256) void k_attn(const _Float16* __restrict__ Qh,
                                              const _Float16* __restrict__ Kh,
                                              const _Float16* __restrict__ Vt,
                                              _Float16* __restrict__ Yh) {
    __shared__ _Float16 lds[8192];
    const int bid = blockIdx.x;
    const int bh = bid & 63;
    const int qt = 15 - (bid >> 6);
    const int tid = threadIdx.x, w = tid >> 6;
    const int l31 = tid & 31, hi = (tid >> 5) & 1;
    const int h16 = hi * 16, h4o = hi * 4;
    const size_t base = (size_t)bh * 2048 * 64;

    const int qabs = qt * 128 + w * 32 + l31;
    h8 qf[4];
#pragma unroll
    for (int dk = 0; dk < 4; ++dk)
        qf[dk] = *(const h8*)(Qh + base + (size_t)qabs * 64 + dk * 16 + hi * 8);

    f16x O0 = {}, O1 = {};
    float m = -1e30f, l = 0.f;

    const int sr = tid >> 3;
    const int sc8 = (tid & 7) * 8;
    const int scb = (tid & 7) * 16;
    const int kbb = 2 * qt + 1;
    const int kbw = 2 * qt + (w >> 1);

    {
#pragma unroll
        for (int j = 0; j < 2; ++j) {
            int row = j * 32 + sr;
            h8 kv = *(const h8*)(Kh + base + (size_t)row * 64 + sc8);
            h8 vv = *(const h8*)(Vt + base + (size_t)row * 2048 + sc8);
            *(h8*)(&lds[SWZI(row, scb)]) = kv;
            *(h8*)(&lds[4096 + SWZI(row, scb)]) = vv;
        }
    }
    __syncthreads();

    for (int kb = 0; kb <= kbb; ++kb) {
        const bool pre = (kb < kbb);
        h8 kn[2], vn[2];
        if (pre) {
#pragma unroll
            for (int j = 0; j < 2; ++j) {
                int row = j * 32 + sr;
                kn[j] = *(const h8*)(Kh + base + (size_t)((kb + 1) * 64 + row) * 64 + sc8);
                vn[j] = *(const h8*)(Vt + base + (size_t)row * 2048 + (kb + 1) * 64 + sc8);
            }
        }

        if (kb <= kbw) {
            f16x S0 = {}, S1 = {};
            __builtin_amdgcn_s_setprio(1);
#pragma unroll
            for (int dk = 0; dk < 4; ++dk) {
                h8 kf0 = *(const h8*)(&lds[SWZI(l31, dk * 32 + h16)]);
                h8 kf1 = *(const h8*)(&lds[SWZI(32 + l31, dk * 32 + h16)]);
                S0 = MFMA32(kf0, qf[dk], S0);
                S1 = MFMA32(kf1, qf[dk], S1);
            }
            __builtin_amdgcn_s_setprio(0);

            if (kb == kbw) {
#pragma unroll
                for (int r = 0; r < 16; ++r) {
                    int key = kb * 64 + (r & 3) + 8 * (r >> 2) + h4o;
                    if (key > qabs) S0[r] = -1e30f;
                    if (key + 32 > qabs) S1[r] = -1e30f;
                }
            }

            float tr[16];
#pragma unroll
            for (int r = 0; r < 16; ++r) tr[r] = fmaxf(S0[r], S1[r]);
#pragma unroll
            for (int st = 8; st >= 1; st >>= 1)
#pragma unroll
                for (int r = 0; r < st; ++r) tr[r] = fmaxf(tr[r], tr[r + st]);
            float pm = fmaxf(tr[0], swap_half(tr[0]));
            if (!__all(pm - m <= 8.f)) {
                float mnew = fmaxf(m, pm);
                float scl = __builtin_amdgcn_exp2f(m - mnew);
                m = mnew;
                l *= scl;
#pragma unroll
                for (int r = 0; r < 16; ++r) { O0[r] *= scl; O1[r] *= scl; }
            }
#pragma unroll
            for (int r = 0; r < 16; ++r) {
                S0[r] = __builtin_amdgcn_exp2f(S0[r] - m);
                S1[r] = __builtin_amdgcn_exp2f(S1[r] - m);
            }
#pragma unroll
            for (int r = 0; r < 16; ++r) tr[r] = S0[r] + S1[r];
#pragma unroll
            for (int st = 8; st >= 1; st >>= 1)
#pragma unroll
                for (int r = 0; r < st; ++r) tr[r] += tr[r + st];
            l += tr[0] + swap_half(tr[0]);

            h8 pb[4];
#pragma unroll
            for (int kk = 0; kk < 4; ++kk) {
                const int bb = (kk & 1) * 8;
                unsigned W0, W1, W2, W3;
                if (kk < 2) {
                    W0 = __builtin_bit_cast(unsigned, __builtin_amdgcn_cvt_pkrtz(S0[bb + 0], S0[bb + 1]));
                    W1 = __builtin_bit_cast(unsigned, __builtin_amdgcn_cvt_pkrtz(S0[bb + 2], S0[bb + 3]));
                    W2 = __builtin_bit_cast(unsigned, __builtin_amdgcn_cvt_pkrtz(S0[bb + 4], S0[bb + 5]));
                    W3 = __builtin_bit_cast(unsigned, __builtin_amdgcn_cvt_pkrtz(S0[bb + 6], S0[bb + 7]));
                } else {
                    W0 = __builtin_bit_cast(unsigned, __builtin_amdgcn_cvt_pkrtz(S1[bb + 0], S1[bb + 1]));
                    W1 = __builtin_bit_cast(unsigned, __builtin_amdgcn_cvt_pkrtz(S1[bb + 2], S1[bb + 3]));
                    W2 = __builtin_bit_cast(unsigned, __builtin_amdgcn_cvt_pkrtz(S1[bb + 4], S1[bb + 5]));
                    W3 = __builtin_bit_cast(unsigned, __builtin_amdgcn_cvt_pkrtz(S1[bb + 6], S1[bb + 7]));
                }
                unsigned E0 = (unsigned)__shfl_xor((int)(hi ? W0 : W2), 32, 64);
                unsigned E1 = (unsigned)__shfl_xor((int)(hi ? W1 : W3), 32, 64);
                u4 wvv;
                wvv[0] = hi ? E0 : W0;
                wvv[1] = hi ? E1 : W1;
                wvv[2] = hi ? W2 : E0;
                wvv[3] = hi ? W3 : E1;
                pb[kk] = __builtin_bit_cast(h8, wvv);
            }

            __builtin_amdgcn_s_setprio(1);
#pragma unroll
            for (int kk = 0; kk < 4; ++kk) {
                h8 vf0 = *(const h8*)(&lds[4096 + SWZI(l31, kk * 32 + h16)]);
                h8 vf1 = *(const h8*)(&lds[4096 + SWZI(32 + l31, kk * 32 + h16)]);
                O0 = MFMA32(vf0, pb[kk], O0);
                O1 = MFMA32(vf1, pb[kk], O1);
            }
            __builtin_amdgcn_s_setprio(0);
        }

        __syncthreads();
        if (pre) {
#pragma unroll
            for (int j = 0; j < 2; ++j) {
                int row = j * 32 + sr;
                *(h8*)(&lds[SWZI(row, scb)]) = kn[j];
                *(h8*)(&lds[4096 + SWZI(row, scb)]) = vn[j];
            }
            __syncthreads();
        }
    }

    __syncthreads();

    {
        float inv = 1.0f / l;
        const int R = w * 32 + l31;
#pragma unroll
        for (int rr = 0; rr < 4; ++rr) {
            h4 a, b;
#pragma unroll
            for (int q = 0; q < 4; ++q) {
                a[q] = (_Float16)(O0[rr * 4 + q] * inv);
                b[q] = (_Float16)(O1[rr * 4 + q] * inv);
            }
            *(h4*)(&lds[SWZI(R, rr * 16 + hi * 8)]) = a;
            *(h4*)(&lds[SWZI(R, 64 + rr * 16 + hi * 8)]) = b;
        }
    }
    __syncthreads();
    {
        const int b = bh >> 4, head = bh & 15;
        const int row = tid >> 1;
#pragma unroll
        for (int i = 0; i < 4; ++i) {
            int seg = (tid & 1) * 4 + i;
            h8 v = *(const h8*)(&lds[SWZI(row, seg * 16)]);
            *(h8*)(Yh + ((size_t)(b * 2048 + qt * 128 + row)) * 1024 + head * 64 + seg * 8) = v;
        }
    }
}

extern "C" void kernel_launch(void* const* d_in, const int* in_sizes, int n_in,
                              void* d_out, int out_size, void* d_ws, size_t ws_size,
                              hipStream_t stream) {
    const float* x  = (const float*)d_in[0];
    const float* Wa = (const float*)d_in[1];
    const float* ba = (const float*)d_in[2];
    const float* Wp = (const float*)d_in[3];
    const float* bp = (const float*)d_in[4];
    float* out = (float*)d_out;

    _Float16* ws = (_Float16*)d_ws;
    const size_t SZ_X = (size_t)8192 * 1024;
    const size_t SZ_WA = (size_t)3072 * 1024;
    const size_t SZ_WP = (size_t)1024 * 1024;
    const size_t SZ_H = (size_t)64 * 2048 * 64;
    _Float16* xh  = ws;
    _Float16* WaT = xh + SZ_X;
    _Float16* WpT = WaT + SZ_WA;
    _Float16* Qh  = WpT + SZ_WP;
    _Float16* Kh  = Qh + SZ_H;
    _Float16* Vth = Kh + SZ_H;    // V transposed: (bh, d, t)
    _Float16* Yh  = Vth + SZ_H;

    k_f32_to_f16<<<8192, 256, 0, stream>>>(x, xh, (int)(SZ_X / 4));
    k_transpose_f16<<<dim3(16, 48), 256, 0, stream>>>(Wa, WaT, 1024, 3072);
    k_transpose_f16<<<dim3(16, 16), 256, 0, stream>>>(Wp, WpT, 1024, 1024);
    // QKV: 256x128 tiles -> grid 32*24 = 768 = exactly 3 rounds of 256 CUs
    k_gemm3<0><<<768, 512, 0, stream>>>(xh, WaT, ba, Qh, Kh, Vth, nullptr,
                                        1024, 3072, 24);
    k_attn<<<1024, 256, 0, stream>>>(Qh, Kh, Vth, Yh);
    // proj: 256x128 tiles -> grid 32*8 = 256 = exactly 1 round
    k_gemm3<1><<<256, 512, 0, stream>>>(Yh, WpT, bp, nullptr, nullptr, nullptr,
                                        out, 1024, 1024, 8);
}

// Round 13
// 187.745 us; speedup vs baseline: 1.0740x; 1.0740x over previous
//
#include <hip/hip_runtime.h>

typedef __attribute__((ext_vector_type(8))) _Float16 h8;
typedef __attribute__((ext_vector_type(4))) _Float16 h4;
typedef __attribute__((ext_vector_type(4))) float f4;
typedef __attribute__((ext_vector_type(16))) float f16x;
typedef __attribute__((ext_vector_type(4))) unsigned u4;

#define MFMA16(a,b,c) __builtin_amdgcn_mfma_f32_16x16x32_f16(a,b,c,0,0,0)
#define MFMA32(a,b,c) __builtin_amdgcn_mfma_f32_32x32x16_f16(a,b,c,0,0,0)

// async global->LDS, 16B per lane; LDS dest = wave-uniform base + lane*16
__device__ inline void gload16(const void* g, void* l) {
    __builtin_amdgcn_global_load_lds(
        (const __attribute__((address_space(1))) void*)g,
        (__attribute__((address_space(3))) void*)l, 16, 0, 0);
}

// partner-half (lane ^ 32) value, semantics-guaranteed
__device__ inline float swap_half(float x) { return __shfl_xor(x, 32, 64); }

// ---------------- fp32 -> f16 elementwise (vectorized) ----------------
__global__ __launch_bounds__(256) void k_f32_to_f16(const float* __restrict__ in,
                                                    _Float16* __restrict__ out, int n4) {
    int i = blockIdx.x * 256 + threadIdx.x;
    if (i < n4) {
        float4 v = ((const float4*)in)[i];
        h4 h;
        h[0] = (_Float16)v.x; h[1] = (_Float16)v.y;
        h[2] = (_Float16)v.z; h[3] = (_Float16)v.w;
        ((h4*)out)[i] = h;
    }
}

// ---------------- fp32 (K,N) -> f16 (N,K) tiled transpose ----------------
__global__ __launch_bounds__(256) void k_transpose_f16(const float* __restrict__ W,
                                                       _Float16* __restrict__ Wt,
                                                       int K, int N) {
    __shared__ float tile[64 * 68];
    const int k0 = blockIdx.x * 64, n0 = blockIdx.y * 64;
    const int t = threadIdx.x;
    const int tr = t >> 4;
    const int tc = t & 15;
#pragma unroll
    for (int i = 0; i < 4; ++i) {
        int r = tr + i * 16;
        float4 v = *(const float4*)(W + (size_t)(k0 + r) * N + n0 + tc * 4);
        *(float4*)(&tile[r * 68 + tc * 4]) = v;
    }
    __syncthreads();
#pragma unroll
    for (int i = 0; i < 4; ++i) {
        int nl = tr + i * 16;
        h4 hv;
#pragma unroll
        for (int j = 0; j < 4; ++j)
            hv[j] = (_Float16)tile[(tc * 4 + j) * 68 + nl];
        *(h4*)(Wt + (size_t)(n0 + nl) * K + k0 + tc * 4) = hv;
    }
}

// ======== QKV GEMM: 256x256, m201-geometry, 4-slot BK=32 sub-tile ring ========
// 8 waves (2Mx4N, per-wave 128x64), 16x16x32 MFMA. Sub-tile t = 2 phases, each:
// {4-8 ds_read_b128 | 2 gload_lds for sub-tile t+3 | raw barrier | setprio(1) +
// 16 MFMA + setprio(0) | barrier}. End-of-subtile wait = vmcnt(8) (= t+2,t+3's
// 8 loads/wave in flight; NEVER 0 in steady state) -> ~3 sub-tiles (~900cy) cover.
// Slot (t+3)&3 was fully read at sub-tile t-1's trailing barrier -> WAR-safe.
// T2 swizzle for 64B rows: LDS(row,seg) holds global seg seg^((row>>1)&3);
// staging source col = ((tid&3)^((tid>>3)&3))*8; read seg = l4^((l15>>1)&3)
// (bases are 16-divisible so the term is thread-constant). 2-way bank alias = free.
// Epilogue: scatter Q/K (B,H,T,64), V^T (B,H,64,T); Q pre-scaled 0.125*log2(e).
__global__ __launch_bounds__(512, 2) void k_gemmA(const _Float16* __restrict__ A,
                                                  const _Float16* __restrict__ Bt,
                                                  const float* __restrict__ bias,
                                                  _Float16* __restrict__ oQ,
                                                  _Float16* __restrict__ oK,
                                                  _Float16* __restrict__ oV,
                                                  int K, int nbn) {
    __shared__ _Float16 As[4][256 * 32];
    __shared__ _Float16 Bs[4][256 * 32];
    const int nwg = gridDim.x;
    const int q8 = nwg >> 3;               // nwg % 8 == 0
    const int wg = (blockIdx.x & 7) * q8 + (blockIdx.x >> 3);   // XCD-chunked, bijective
    const int bm = (wg / nbn) * 256, bn = (wg % nbn) * 256;
    const int tid = threadIdx.x, lane = tid & 63, wv = tid >> 6;
    const int wm = wv >> 2, wn = wv & 3;   // per-wave out: 128 x 64
    const int l15 = lane & 15, l4 = lane >> 4;
    const int rseg8 = (l4 ^ ((l15 >> 1) & 3)) * 8;   // swizzled read seg (f16 units)

    // staging: instr covers 128 rows (4 threads x 16B per 64B row)
    const int srow = tid >> 2;                         // 0..127
    const int sseg = ((tid & 3) ^ ((tid >> 3) & 3));   // pre-swizzled source seg
    const _Float16* Ag = A + (size_t)(bm + srow) * K + sseg * 8;
    const _Float16* Bg = Bt + (size_t)(bn + srow) * K + sseg * 8;

    f4 acc[8][4] = {};
    const int NSUB = K >> 5;               // 32

    auto STAGE_A = [&](int t3, int s) {
        const size_t ko = (size_t)t3 * 32;
        gload16(Ag + ko, &As[s][wv * 512]);
        gload16(Ag + (size_t)128 * K + ko, &As[s][4096 + wv * 512]);
    };
    auto STAGE_B = [&](int t3, int s) {
        const size_t ko = (size_t)t3 * 32;
        gload16(Bg + ko, &Bs[s][wv * 512]);
        gload16(Bg + (size_t)128 * K + ko, &Bs[s][4096 + wv * 512]);
    };

    // prologue: sub-tiles 0,1,2 -> slots 0,1,2
    STAGE_A(0, 0); STAGE_B(0, 0);
    STAGE_A(1, 1); STAGE_B(1, 1);
    STAGE_A(2, 2); STAGE_B(2, 2);
    asm volatile("s_waitcnt vmcnt(8)" ::: "memory");   // sub-tile 0 resident
    __builtin_amdgcn_s_barrier();

    for (int t = 0; t < NSUB; ++t) {
        const int s = t & 3, s3 = (t + 3) & 3;
        const bool st = (t + 3 < NSUB);
        const _Float16* Ac = As[s];
        const _Float16* Bc = Bs[s];

        // ---- phase A: af[0..3] + bf[0..3] reads, stage A(t+3), 16 MFMA ----
        h8 af[4], bf[4];
#pragma unroll
        for (int mf = 0; mf < 4; ++mf)
            af[mf] = *(const h8*)(&Ac[(wm * 128 + mf * 16 + l15) * 32 + rseg8]);
#pragma unroll
        for (int nf = 0; nf < 4; ++nf)
            bf[nf] = *(const h8*)(&Bc[(wn * 64 + nf * 16 + l15) * 32 + rseg8]);
        if (st) STAGE_A(t + 3, s3);
        __builtin_amdgcn_s_barrier();
        __builtin_amdgcn_s_setprio(1);
#pragma unroll
        for (int mf = 0; mf < 4; ++mf)
#pragma unroll
            for (int nf = 0; nf < 4; ++nf)
                acc[mf][nf] = MFMA16(af[mf], bf[nf], acc[mf][nf]);
        __builtin_amdgcn_s_setprio(0);
        __builtin_amdgcn_s_barrier();

        // ---- phase B: af[4..7] reads, stage B(t+3), counted vmcnt, 16 MFMA ----
        h8 ag[4];
#pragma unroll
        for (int mf = 0; mf < 4; ++mf)
            ag[mf] = *(const h8*)(&Ac[(wm * 128 + (mf + 4) * 16 + l15) * 32 + rseg8]);
        if (st) STAGE_B(t + 3, s3);
        // T4: wait until only sub-tiles t+2,t+3 outstanding => t+1 resident
        if (t + 3 < NSUB)      asm volatile("s_waitcnt vmcnt(8)" ::: "memory");
        else if (t + 2 < NSUB) asm volatile("s_waitcnt vmcnt(4)" ::: "memory");
        else if (t + 1 < NSUB) asm volatile("s_waitcnt vmcnt(0)" ::: "memory");
        __builtin_amdgcn_s_barrier();
        __builtin_amdgcn_s_setprio(1);
#pragma unroll
        for (int mf = 0; mf < 4; ++mf)
#pragma unroll
            for (int nf = 0; nf < 4; ++nf)
                acc[mf + 4][nf] = MFMA16(ag[mf], bf[nf], acc[mf + 4][nf]);
        __builtin_amdgcn_s_setprio(0);
        __builtin_amdgcn_s_barrier();
    }

    // epilogue: scatter into Q/K (B,H,T,64) and V^T (B,H,64,T)
#pragma unroll
    for (int mf = 0; mf < 8; ++mf) {
#pragma unroll
        for (int nf = 0; nf < 4; ++nf) {
            const int col = bn + wn * 64 + nf * 16 + l15;
            const float bv = bias[col];
            const int rb = bm + wm * 128 + mf * 16 + l4 * 4;
            const int which = col >> 10;
            const int hh = (col & 1023) >> 6, dd = col & 63;
            if (which == 2) {
                const int b = rb >> 11, tq = rb & 2047;
                h4 pv;
#pragma unroll
                for (int i = 0; i < 4; ++i) pv[i] = (_Float16)(acc[mf][nf][i] + bv);
                *(h4*)(oV + ((size_t)(b * 16 + hh) * 64 + dd) * 2048 + tq) = pv;
            } else {
                _Float16* dst = which == 0 ? oQ : oK;
                const float scl = which == 0 ? 0.18033688011112042f : 1.0f; // 0.125*log2(e)
#pragma unroll
                for (int i = 0; i < 4; ++i) {
                    const int row = rb + i;
                    const int b = row >> 11, tq = row & 2047;
                    dst[(((size_t)b * 16 + hh) * 2048 + tq) * 64 + dd] =
                        (_Float16)((acc[mf][nf][i] + bv) * scl);
                }
            }
        }
    }
}

// ======== proj GEMM: 256x128 fine-interleaved 4-phase (r11 known-good) ========
__global__ __launch_bounds__(512, 2) void k_gemmP(const _Float16* __restrict__ A,
                                                  const _Float16* __restrict__ Bt,
                                                  const float* __restrict__ bias,
                                                  float* __restrict__ oF,
                                                  int K, int N, int nbn) {
    __shared__ _Float16 As[2][256 * 64];
    __shared__ _Float16 Bs[2][128 * 64];
    const int nwg = gridDim.x;
    const int q8 = nwg >> 3;
    const int wg = (blockIdx.x & 7) * q8 + (blockIdx.x >> 3);
    const int bm = (wg / nbn) * 256, bn = (wg % nbn) * 128;
    const int tid = threadIdx.x, lane = tid & 63, wv = tid >> 6;
    const int wm = wv >> 2, wn = wv & 3;
    const int l15 = lane & 15, l4 = lane >> 4;
    const int sr8 = lane >> 3;
    const int sseg = ((lane & 7) ^ sr8) * 8;
    const _Float16* Ag = A + (size_t)(bm + wv * 8 + sr8) * K + sseg;
    const _Float16* Bg = Bt + (size_t)(bn + wv * 8 + sr8) * K + sseg;
    f4 acc[8][2] = {};

    const int NT = K >> 6;
#pragma unroll
    for (int j = 0; j < 4; ++j) gload16(Ag + (size_t)j * 64 * K, &As[0][(j * 64 + wv * 8) * 64]);
#pragma unroll
    for (int j = 0; j < 2; ++j) gload16(Bg + (size_t)j * 64 * K, &Bs[0][(j * 64 + wv * 8) * 64]);
    asm volatile("s_waitcnt vmcnt(0)" ::: "memory");
    __builtin_amdgcn_s_barrier();

    for (int tau = 0; tau < NT; ++tau) {
        const int s = tau & 1;
        const bool pre = (tau + 1 < NT);
        const size_t ko = (size_t)(tau + 1) << 6;

        h8 bf[2][2];
#pragma unroll
        for (int nf = 0; nf < 2; ++nf)
#pragma unroll
            for (int ks = 0; ks < 2; ++ks) {
                const int row = wn * 32 + nf * 16 + l15;
                const int seg = (ks * 4 + l4) ^ (l15 & 7);
                bf[nf][ks] = *(const h8*)(&Bs[s][row * 64 + seg * 8]);
            }

#pragma unroll
        for (int q = 0; q < 4; ++q) {
            h8 af[2][2];
#pragma unroll
            for (int mi = 0; mi < 2; ++mi)
#pragma unroll
                for (int ks = 0; ks < 2; ++ks) {
                    const int row = wm * 128 + (2 * q + mi) * 16 + l15;
                    const int seg = (ks * 4 + l4) ^ (l15 & 7);
                    af[mi][ks] = *(const h8*)(&As[s][row * 64 + seg * 8]);
                }
            if (pre) {
                if (q == 0) {
                    gload16(Ag + ko, &As[s ^ 1][(wv * 8) * 64]);
                    gload16(Ag + (size_t)64 * K + ko, &As[s ^ 1][(64 + wv * 8) * 64]);
                } else if (q == 1) {
                    gload16(Ag + (size_t)128 * K + ko, &As[s ^ 1][(128 + wv * 8) * 64]);
                    gload16(Ag + (size_t)192 * K + ko, &As[s ^ 1][(192 + wv * 8) * 64]);
                } else if (q == 2) {
#pragma unroll
                    for (int j = 0; j < 2; ++j)
                        gload16(Bg + (size_t)j * 64 * K + ko, &Bs[s ^ 1][(j * 64 + wv * 8) * 64]);
                } else {
                    asm volatile("s_waitcnt vmcnt(0)" ::: "memory");
                }
            }
            __builtin_amdgcn_s_barrier();
            __builtin_amdgcn_s_setprio(1);
#pragma unroll
            for (int mi = 0; mi < 2; ++mi)
#pragma unroll
                for (int nf = 0; nf < 2; ++nf)
#pragma unroll
                    for (int ks = 0; ks < 2; ++ks)
                        acc[2 * q + mi][nf] = MFMA16(af[mi][ks], bf[nf][ks], acc[2 * q + mi][nf]);
            __builtin_amdgcn_s_setprio(0);
            __builtin_amdgcn_s_barrier();
        }
    }

#pragma unroll
    for (int mf = 0; mf < 8; ++mf)
#pragma unroll
        for (int nf = 0; nf < 2; ++nf) {
            const int col = bn + wn * 32 + nf * 16 + l15;
            const float bv = bias[col];
            const int rb = bm + wm * 128 + mf * 16 + l4 * 4;
#pragma unroll
            for (int i = 0; i < 4; ++i)
                oF[(size_t)(rb + i) * N + col] = acc[mf][nf][i] + bv;
        }
}

// ---------------- causal flash attention: 4 waves x 32 q-rows, shared 64-key K/V tile ----------------
#define SWZI(row, cb) ((((row) << 7) + ((cb) ^ ((((row) & 7) << 4)))) >> 1)

__global__ __launch_bounds__(256) void k_attn(const _Float16* __restrict__ Qh,
                                              const _Float16* __restrict__ Kh,
                                              const _Float16* __restrict__ Vt,
                                              _Float16* __restrict__ Yh) {
    __shared__ _Float16 lds[8192];
    const int bid = blockIdx.x;
    const int bh = bid & 63;
    const int qt = 15 - (bid >> 6);
    const int tid = threadIdx.x, w = tid >> 6;
    const int l31 = tid & 31, hi = (tid >> 5) & 1;
    const int h16 = hi * 16, h4o = hi * 4;
    const size_t base = (size_t)bh * 2048 * 64;

    const int qabs = qt * 128 + w * 32 + l31;
    h8 qf[4];
#pragma unroll
    for (int dk = 0; dk < 4; ++dk)
        qf[dk] = *(const h8*)(Qh + base + (size_t)qabs * 64 + dk * 16 + hi * 8);

    f16x O0 = {}, O1 = {};
    float m = -1e30f, l = 0.f;

    const int sr = tid >> 3;
    const int sc8 = (tid & 7) * 8;
    const int scb = (tid & 7) * 16;
    const int kbb = 2 * qt + 1;
    const int kbw = 2 * qt + (w >> 1);

    {
#pragma unroll
        for (int j = 0; j < 2; ++j) {
            int row = j * 32 + sr;
            h8 kv = *(const h8*)(Kh + base + (size_t)row * 64 + sc8);
            h8 vv = *(const h8*)(Vt + base + (size_t)row * 2048 + sc8);
            *(h8*)(&lds[SWZI(row, scb)]) = kv;
            *(h8*)(&lds[4096 + SWZI(row, scb)]) = vv;
        }
    }
    __syncthreads();

    for (int kb = 0; kb <= kbb; ++kb) {
        const bool pre = (kb < kbb);
        h8 kn[2], vn[2];
        if (pre) {
#pragma unroll
            for (int j = 0; j < 2; ++j) {
                int row = j * 32 + sr;
                kn[j] = *(const h8*)(Kh + base + (size_t)((kb + 1) * 64 + row) * 64 + sc8);
                vn[j] = *(const h8*)(Vt + base + (size_t)row * 2048 + (kb + 1) * 64 + sc8);
            }
        }

        if (kb <= kbw) {
            f16x S0 = {}, S1 = {};
            __builtin_amdgcn_s_setprio(1);
#pragma unroll
            for (int dk = 0; dk < 4; ++dk) {
                h8 kf0 = *(const h8*)(&lds[SWZI(l31, dk * 32 + h16)]);
                h8 kf1 = *(const h8*)(&lds[SWZI(32 + l31, dk * 32 + h16)]);
                S0 = MFMA32(kf0, qf[dk], S0);
                S1 = MFMA32(kf1, qf[dk], S1);
            }
            __builtin_amdgcn_s_setprio(0);

            if (kb == kbw) {
#pragma unroll
                for (int r = 0; r < 16; ++r) {
                    int key = kb * 64 + (r & 3) + 8 * (r >> 2) + h4o;
                    if (key > qabs) S0[r] = -1e30f;
                    if (key + 32 > qabs) S1[r] = -1e30f;
                }
            }

            float tr[16];
#pragma unroll
            for (int r = 0; r < 16; ++r) tr[r] = fmaxf(S0[r], S1[r]);
#pragma unroll
            for (int st = 8; st >= 1; st >>= 1)
#pragma unroll
                for (int r = 0; r < st; ++r) tr[r] = fmaxf(tr[r], tr[r + st]);
            float pm = fmaxf(tr[0], swap_half(tr[0]));
            if (!__all(pm - m <= 8.f)) {
                float mnew = fmaxf(m, pm);
                float scl = __builtin_amdgcn_exp2f(m - mnew);
                m = mnew;
                l *= scl;
#pragma unroll
                for (int r = 0; r < 16; ++r) { O0[r] *= scl; O1[r] *= scl; }
            }
#pragma unroll
            for (int r = 0; r < 16; ++r) {
                S0[r] = __builtin_amdgcn_exp2f(S0[r] - m);
                S1[r] = __builtin_amdgcn_exp2f(S1[r] - m);
            }
#pragma unroll
            for (int r = 0; r < 16; ++r) tr[r] = S0[r] + S1[r];
#pragma unroll
            for (int st = 8; st >= 1; st >>= 1)
#pragma unroll
                for (int r = 0; r < st; ++r) tr[r] += tr[r + st];
            l += tr[0] + swap_half(tr[0]);

            h8 pb[4];
#pragma unroll
            for (int kk = 0; kk < 4; ++kk) {
                const int bb = (kk & 1) * 8;
                unsigned W0, W1, W2, W3;
                if (kk < 2) {
                    W0 = __builtin_bit_cast(unsigned, __builtin_amdgcn_cvt_pkrtz(S0[bb + 0], S0[bb + 1]));
                    W1 = __builtin_bit_cast(unsigned, __builtin_amdgcn_cvt_pkrtz(S0[bb + 2], S0[bb + 3]));
                    W2 = __builtin_bit_cast(unsigned, __builtin_amdgcn_cvt_pkrtz(S0[bb + 4], S0[bb + 5]));
                    W3 = __builtin_bit_cast(unsigned, __builtin_amdgcn_cvt_pkrtz(S0[bb + 6], S0[bb + 7]));
                } else {
                    W0 = __builtin_bit_cast(unsigned, __builtin_amdgcn_cvt_pkrtz(S1[bb + 0], S1[bb + 1]));
                    W1 = __builtin_bit_cast(unsigned, __builtin_amdgcn_cvt_pkrtz(S1[bb + 2], S1[bb + 3]));
                    W2 = __builtin_bit_cast(unsigned, __builtin_amdgcn_cvt_pkrtz(S1[bb + 4], S1[bb + 5]));
                    W3 = __builtin_bit_cast(unsigned, __builtin_amdgcn_cvt_pkrtz(S1[bb + 6], S1[bb + 7]));
                }
                unsigned E0 = (unsigned)__shfl_xor((int)(hi ? W0 : W2), 32, 64);
                unsigned E1 = (unsigned)__shfl_xor((int)(hi ? W1 : W3), 32, 64);
                u4 wvv;
                wvv[0] = hi ? E0 : W0;
                wvv[1] = hi ? E1 : W1;
                wvv[2] = hi ? W2 : E0;
                wvv[3] = hi ? W3 : E1;
                pb[kk] = __builtin_bit_cast(h8, wvv);
            }

            __builtin_amdgcn_s_setprio(1);
#pragma unroll
            for (int kk = 0; kk < 4; ++kk) {
                h8 vf0 = *(const h8*)(&lds[4096 + SWZI(l31, kk * 32 + h16)]);
                h8 vf1 = *(const h8*)(&lds[4096 + SWZI(32 + l31, kk * 32 + h16)]);
                O0 = MFMA32(vf0, pb[kk], O0);
                O1 = MFMA32(vf1, pb[kk], O1);
            }
            __builtin_amdgcn_s_setprio(0);
        }

        __syncthreads();
        if (pre) {
#pragma unroll
            for (int j = 0; j < 2; ++j) {
                int row = j * 32 + sr;
                *(h8*)(&lds[SWZI(row, scb)]) = kn[j];
                *(h8*)(&lds[4096 + SWZI(row, scb)]) = vn[j];
            }
            __syncthreads();
        }
    }

    __syncthreads();

    {
        float inv = 1.0f / l;
        const int R = w * 32 + l31;
#pragma unroll
        for (int rr = 0; rr < 4; ++rr) {
            h4 a, b;
#pragma unroll
            for (int q = 0; q < 4; ++q) {
                a[q] = (_Float16)(O0[rr * 4 + q] * inv);
                b[q] = (_Float16)(O1[rr * 4 + q] * inv);
            }
            *(h4*)(&lds[SWZI(R, rr * 16 + hi * 8)]) = a;
            *(h4*)(&lds[SWZI(R, 64 + rr * 16 + hi * 8)]) = b;
        }
    }
    __syncthreads();
    {
        const int b = bh >> 4, head = bh & 15;
        const int row = tid >> 1;
#pragma unroll
        for (int i = 0; i < 4; ++i) {
            int seg = (tid & 1) * 4 + i;
            h8 v = *(const h8*)(&lds[SWZI(row, seg * 16)]);
            *(h8*)(Yh + ((size_t)(b * 2048 + qt * 128 + row)) * 1024 + head * 64 + seg * 8) = v;
        }
    }
}

extern "C" void kernel_launch(void* const* d_in, const int* in_sizes, int n_in,
                              void* d_out, int out_size, void* d_ws, size_t ws_size,
                              hipStream_t stream) {
    const float* x  = (const float*)d_in[0];
    const float* Wa = (const float*)d_in[1];
    const float* ba = (const float*)d_in[2];
    const float* Wp = (const float*)d_in[3];
    const float* bp = (const float*)d_in[4];
    float* out = (float*)d_out;

    _Float16* ws = (_Float16*)d_ws;
    const size_t SZ_X = (size_t)8192 * 1024;
    const size_t SZ_WA = (size_t)3072 * 1024;
    const size_t SZ_WP = (size_t)1024 * 1024;
    const size_t SZ_H = (size_t)64 * 2048 * 64;
    _Float16* xh  = ws;
    _Float16* WaT = xh + SZ_X;
    _Float16* WpT = WaT + SZ_WA;
    _Float16* Qh  = WpT + SZ_WP;
    _Float16* Kh  = Qh + SZ_H;
    _Float16* Vth = Kh + SZ_H;    // V transposed: (bh, d, t)
    _Float16* Yh  = Vth + SZ_H;

    k_f32_to_f16<<<8192, 256, 0, stream>>>(x, xh, (int)(SZ_X / 4));
    k_transpose_f16<<<dim3(16, 48), 256, 0, stream>>>(Wa, WaT, 1024, 3072);
    k_transpose_f16<<<dim3(16, 16), 256, 0, stream>>>(Wp, WpT, 1024, 1024);
    // QKV: 256x256 tiles -> grid 32*12 = 384 (1.5 rounds, accepted for phase balance)
    k_gemmA<<<384, 512, 0, stream>>>(xh, WaT, ba, Qh, Kh, Vth, 1024, 12);
    k_attn<<<1024, 256, 0, stream>>>(Qh, Kh, Vth, Yh);
    // proj: 256x128 tiles -> grid 32*8 = 256 = exactly 1 round
    k_gemmP<<<256, 512, 0, stream>>>(Yh, WpT, bp, out, 1024, 1024, 8);
}

// Round 14
// 182.992 us; speedup vs baseline: 1.1019x; 1.0260x over previous
//
#include <hip/hip_runtime.h>

typedef __attribute__((ext_vector_type(8))) _Float16 h8;
typedef __attribute__((ext_vector_type(4))) _Float16 h4;
typedef __attribute__((ext_vector_type(4))) float f4;
typedef __attribute__((ext_vector_type(16))) float f16x;
typedef __attribute__((ext_vector_type(4))) unsigned u4;

#define MFMA16(a,b,c) __builtin_amdgcn_mfma_f32_16x16x32_f16(a,b,c,0,0,0)
#define MFMA32(a,b,c) __builtin_amdgcn_mfma_f32_32x32x16_f16(a,b,c,0,0,0)

// async global->LDS, 16B per lane; LDS dest = wave-uniform base + lane*16
__device__ inline void gload16(const void* g, void* l) {
    __builtin_amdgcn_global_load_lds(
        (const __attribute__((address_space(1))) void*)g,
        (__attribute__((address_space(3))) void*)l, 16, 0, 0);
}

// partner-half (lane ^ 32) value, semantics-guaranteed
__device__ inline float swap_half(float x) { return __shfl_xor(x, 32, 64); }

// ---------------- fp32 (K,N) -> f16 (N,K) tiled transpose ----------------
__global__ __launch_bounds__(256) void k_transpose_f16(const float* __restrict__ W,
                                                       _Float16* __restrict__ Wt,
                                                       int K, int N) {
    __shared__ float tile[64 * 68];
    const int k0 = blockIdx.x * 64, n0 = blockIdx.y * 64;
    const int t = threadIdx.x;
    const int tr = t >> 4;
    const int tc = t & 15;
#pragma unroll
    for (int i = 0; i < 4; ++i) {
        int r = tr + i * 16;
        float4 v = *(const float4*)(W + (size_t)(k0 + r) * N + n0 + tc * 4);
        *(float4*)(&tile[r * 68 + tc * 4]) = v;
    }
    __syncthreads();
#pragma unroll
    for (int i = 0; i < 4; ++i) {
        int nl = tr + i * 16;
        h4 hv;
#pragma unroll
        for (int j = 0; j < 4; ++j)
            hv[j] = (_Float16)tile[(tc * 4 + j) * 68 + nl];
        *(h4*)(Wt + (size_t)(n0 + nl) * K + k0 + tc * 4) = hv;
    }
}

// ======== QKV GEMM (r8 structure + fused f32->f16 A-conversion) ========
// 128x128 tile, BK=32, 2-slot double buffer, 6 blocks/CU (best-measured config).
// A (= x, fp32) is reg-staged: 2x float4 load -> cvt -> ds_write_b128 at the SAME
// linear LDS address gload16 would use. B (= WaT, f16) stays global_load_lds.
// Loads for tile t+1 issue at iteration top (MFMA-phase cover); convert+write land
// after the MFMAs, before the single barrier (same WAR-safe pattern as r8).
// Epilogue: scatter Q/K (B,H,T,64), V^T (B,H,64,T); Q pre-scaled 0.125*log2(e).
__global__ __launch_bounds__(256) void k_gemmQKV(const float* __restrict__ X,
                                                 const _Float16* __restrict__ Bt,
                                                 const float* __restrict__ bias,
                                                 _Float16* __restrict__ oQ,
                                                 _Float16* __restrict__ oK,
                                                 _Float16* __restrict__ oV,
                                                 int M, int N, int K) {
    __shared__ _Float16 As[2][128 * 32];  // linear [row][k], 64B rows
    __shared__ _Float16 Bs[2][128 * 32];
    const int tid = threadIdx.x;
    const int lane = tid & 63, wv = tid >> 6;
    const int wm = wv >> 1, wn = wv & 1;
    const int l15 = lane & 15, l4 = lane >> 4;
    const int bm = blockIdx.x * 128, bn = blockIdx.y * 128;
    f4 acc[4][4] = {};

    const int srow = lane >> 2, scol = (lane & 3) * 8;
    const float*    Xg = X  + (size_t)(bm + srow) * K + scol;
    const _Float16* Bg = Bt + (size_t)(bn + srow) * K + scol;

    float a8[2][8];
    auto LOADA = [&](int k0) {
#pragma unroll
        for (int j = 0; j < 2; ++j) {
            const float* p = Xg + (size_t)((wv * 2 + j) * 16) * K + k0;
            *(float4*)&a8[j][0] = *(const float4*)(p);
            *(float4*)&a8[j][4] = *(const float4*)(p + 4);
        }
    };
    auto WRITEA = [&](int s) {
#pragma unroll
        for (int j = 0; j < 2; ++j) {
            h8 cv;
#pragma unroll
            for (int e = 0; e < 8; ++e) cv[e] = (_Float16)a8[j][e];
            *(h8*)(&As[s][(wv * 2 + j) * 512 + lane * 8]) = cv;   // = gload16 dest
        }
    };
    auto STAGEB = [&](int k0, int s) {
#pragma unroll
        for (int j = 0; j < 2; ++j)
            gload16(Bg + (size_t)((wv * 2 + j) * 16) * K + k0, &Bs[s][(wv * 2 + j) * 512]);
    };

    // prologue: tile 0 -> slot 0
    LOADA(0);
    STAGEB(0, 0);
    WRITEA(0);                 // compiler waits vmcnt for a8 regs
    __syncthreads();           // drains B DMA + ds_writes

    for (int k0 = 0; k0 < K; k0 += 32) {
        const int s = (k0 >> 5) & 1;
        const bool pre = (k0 + 32 < K);
        if (pre) {
            LOADA(k0 + 32);            // f32 A loads fly under the MFMAs
            STAGEB(k0 + 32, s ^ 1);    // B DMA flies under the MFMAs
        }

        const _Float16* Ac = As[s];
        const _Float16* Bc = Bs[s];
        h8 af[4], bf[4];
#pragma unroll
        for (int i = 0; i < 4; ++i)
            af[i] = *(const h8*)(&Ac[(wm * 64 + i * 16 + l15) * 32 + l4 * 8]);
#pragma unroll
        for (int i = 0; i < 4; ++i)
            bf[i] = *(const h8*)(&Bc[(wn * 64 + i * 16 + l15) * 32 + l4 * 8]);
        __builtin_amdgcn_s_setprio(1);
#pragma unroll
        for (int mi = 0; mi < 4; ++mi)
#pragma unroll
            for (int ni = 0; ni < 4; ++ni)
                acc[mi][ni] = MFMA16(af[mi], bf[ni], acc[mi][ni]);
        __builtin_amdgcn_s_setprio(0);

        if (pre) WRITEA(s ^ 1);        // convert + ds_write next A tile
        __syncthreads();               // all waves done reading slot s; writes visible
    }

    // epilogue: scatter into Q/K (B,H,T,64) and V^T (B,H,64,T)
#pragma unroll
    for (int mi = 0; mi < 4; ++mi) {
#pragma unroll
        for (int ni = 0; ni < 4; ++ni) {
            int col = bn + wn * 64 + ni * 16 + l15;
            float bv = bias[col];
            int rb = bm + wm * 64 + mi * 16 + l4 * 4;
            int which = col >> 10, n1 = col & 1023;
            int hh = n1 >> 6, dd = n1 & 63;
            if (which == 2) {
                int b = rb >> 11, tq = rb & 2047;
                h4 pv;
#pragma unroll
                for (int i = 0; i < 4; ++i) pv[i] = (_Float16)(acc[mi][ni][i] + bv);
                *(h4*)(oV + ((size_t)(b * 16 + hh) * 64 + dd) * 2048 + tq) = pv;
            } else {
                _Float16* dst = which == 0 ? oQ : oK;
                const float scl = which == 0 ? 0.18033688011112042f : 1.0f; // 0.125*log2(e)
#pragma unroll
                for (int i = 0; i < 4; ++i) {
                    int row = rb + i;
                    int b = row >> 11, tq = row & 2047;
                    dst[(((size_t)b * 16 + hh) * 2048 + tq) * 64 + dd] =
                        (_Float16)((acc[mi][ni][i] + bv) * scl);
                }
            }
        }
    }
}

// ======== proj GEMM: r8's 128x128 2-slot double-buffered gload_lds, f32 out ========
__global__ __launch_bounds__(256) void k_gemmP(const _Float16* __restrict__ A,
                                               const _Float16* __restrict__ Bt,
                                               const float* __restrict__ bias,
                                               float* __restrict__ oF,
                                               int M, int N, int K) {
    __shared__ _Float16 As[2][128 * 32];
    __shared__ _Float16 Bs[2][128 * 32];
    const int tid = threadIdx.x;
    const int lane = tid & 63, wv = tid >> 6;
    const int wm = wv >> 1, wn = wv & 1;
    const int l15 = lane & 15, l4 = lane >> 4;
    const int bm = blockIdx.x * 128, bn = blockIdx.y * 128;
    f4 acc[4][4] = {};

    const int srow = lane >> 2, scol = (lane & 3) * 8;
    const _Float16* Ag = A + (size_t)(bm + srow) * K + scol;
    const _Float16* Bg = Bt + (size_t)(bn + srow) * K + scol;

#pragma unroll
    for (int j = 0; j < 2; ++j) {
        const int rb_ = (wv * 2 + j) * 16;
        gload16(Ag + (size_t)rb_ * K, &As[0][(wv * 2 + j) * 512]);
        gload16(Bg + (size_t)rb_ * K, &Bs[0][(wv * 2 + j) * 512]);
    }
    asm volatile("s_waitcnt vmcnt(0)" ::: "memory");
    __syncthreads();

    for (int k0 = 0; k0 < K; k0 += 32) {
        const int s = (k0 >> 5) & 1;
        if (k0 + 32 < K) {
#pragma unroll
            for (int j = 0; j < 2; ++j) {
                const int rb_ = (wv * 2 + j) * 16;
                gload16(Ag + (size_t)rb_ * K + k0 + 32, &As[s ^ 1][(wv * 2 + j) * 512]);
                gload16(Bg + (size_t)rb_ * K + k0 + 32, &Bs[s ^ 1][(wv * 2 + j) * 512]);
            }
        }

        const _Float16* Ac = As[s];
        const _Float16* Bc = Bs[s];
        h8 af[4], bf[4];
#pragma unroll
        for (int i = 0; i < 4; ++i)
            af[i] = *(const h8*)(&Ac[(wm * 64 + i * 16 + l15) * 32 + l4 * 8]);
#pragma unroll
        for (int i = 0; i < 4; ++i)
            bf[i] = *(const h8*)(&Bc[(wn * 64 + i * 16 + l15) * 32 + l4 * 8]);
        __builtin_amdgcn_s_setprio(1);
#pragma unroll
        for (int mi = 0; mi < 4; ++mi)
#pragma unroll
            for (int ni = 0; ni < 4; ++ni)
                acc[mi][ni] = MFMA16(af[mi], bf[ni], acc[mi][ni]);
        __builtin_amdgcn_s_setprio(0);

        asm volatile("s_waitcnt vmcnt(0)" ::: "memory");
        __syncthreads();
    }

#pragma unroll
    for (int mi = 0; mi < 4; ++mi)
#pragma unroll
        for (int ni = 0; ni < 4; ++ni) {
            int col = bn + wn * 64 + ni * 16 + l15;
            float bv = bias[col];
            int rb = bm + wm * 64 + mi * 16 + l4 * 4;
#pragma unroll
            for (int i = 0; i < 4; ++i)
                oF[(size_t)(rb + i) * N + col] = acc[mi][ni][i] + bv;
        }
}

// ---------------- causal flash attention: 4 waves x 32 q-rows, shared 64-key K/V tile ----------------
#define SWZI(row, cb) ((((row) << 7) + ((cb) ^ ((((row) & 7) << 4)))) >> 1)

__global__ __launch_bounds__(256) void k_attn(const _Float16* __restrict__ Qh,
                                              const _Float16* __restrict__ Kh,
                                              const _Float16* __restrict__ Vt,
                                              _Float16* __restrict__ Yh) {
    __shared__ _Float16 lds[8192];
    const int bid = blockIdx.x;
    const int bh = bid & 63;
    const int qt = 15 - (bid >> 6);
    const int tid = threadIdx.x, w = tid >> 6;
    const int l31 = tid & 31, hi = (tid >> 5) & 1;
    const int h16 = hi * 16, h4o = hi * 4;
    const size_t base = (size_t)bh * 2048 * 64;

    const int qabs = qt * 128 + w * 32 + l31;
    h8 qf[4];
#pragma unroll
    for (int dk = 0; dk < 4; ++dk)
        qf[dk] = *(const h8*)(Qh + base + (size_t)qabs * 64 + dk * 16 + hi * 8);

    f16x O0 = {}, O1 = {};
    float m = -1e30f, l = 0.f;

    const int sr = tid >> 3;
    const int sc8 = (tid & 7) * 8;
    const int scb = (tid & 7) * 16;
    const int kbb = 2 * qt + 1;
    const int kbw = 2 * qt + (w >> 1);

    {
#pragma unroll
        for (int j = 0; j < 2; ++j) {
            int row = j * 32 + sr;
            h8 kv = *(const h8*)(Kh + base + (size_t)row * 64 + sc8);
            h8 vv = *(const h8*)(Vt + base + (size_t)row * 2048 + sc8);
            *(h8*)(&lds[SWZI(row, scb)]) = kv;
            *(h8*)(&lds[4096 + SWZI(row, scb)]) = vv;
        }
    }
    __syncthreads();

    for (int kb = 0; kb <= kbb; ++kb) {
        const bool pre = (kb < kbb);
        h8 kn[2], vn[2];
        if (pre) {
#pragma unroll
            for (int j = 0; j < 2; ++j) {
                int row = j * 32 + sr;
                kn[j] = *(const h8*)(Kh + base + (size_t)((kb + 1) * 64 + row) * 64 + sc8);
                vn[j] = *(const h8*)(Vt + base + (size_t)row * 2048 + (kb + 1) * 64 + sc8);
            }
        }

        if (kb <= kbw) {
            f16x S0 = {}, S1 = {};
            __builtin_amdgcn_s_setprio(1);
#pragma unroll
            for (int dk = 0; dk < 4; ++dk) {
                h8 kf0 = *(const h8*)(&lds[SWZI(l31, dk * 32 + h16)]);
                h8 kf1 = *(const h8*)(&lds[SWZI(32 + l31, dk * 32 + h16)]);
                S0 = MFMA32(kf0, qf[dk], S0);
                S1 = MFMA32(kf1, qf[dk], S1);
            }
            __builtin_amdgcn_s_setprio(0);

            if (kb == kbw) {
#pragma unroll
                for (int r = 0; r < 16; ++r) {
                    int key = kb * 64 + (r & 3) + 8 * (r >> 2) + h4o;
                    if (key > qabs) S0[r] = -1e30f;
                    if (key + 32 > qabs) S1[r] = -1e30f;
                }
            }

            float tr[16];
#pragma unroll
            for (int r = 0; r < 16; ++r) tr[r] = fmaxf(S0[r], S1[r]);
#pragma unroll
            for (int st = 8; st >= 1; st >>= 1)
#pragma unroll
                for (int r = 0; r < st; ++r) tr[r] = fmaxf(tr[r], tr[r + st]);
            float pm = fmaxf(tr[0], swap_half(tr[0]));
            if (!__all(pm - m <= 8.f)) {
                float mnew = fmaxf(m, pm);
                float scl = __builtin_amdgcn_exp2f(m - mnew);
                m = mnew;
                l *= scl;
#pragma unroll
                for (int r = 0; r < 16; ++r) { O0[r] *= scl; O1[r] *= scl; }
            }
#pragma unroll
            for (int r = 0; r < 16; ++r) {
                S0[r] = __builtin_amdgcn_exp2f(S0[r] - m);
                S1[r] = __builtin_amdgcn_exp2f(S1[r] - m);
            }
#pragma unroll
            for (int r = 0; r < 16; ++r) tr[r] = S0[r] + S1[r];
#pragma unroll
            for (int st = 8; st >= 1; st >>= 1)
#pragma unroll
                for (int r = 0; r < st; ++r) tr[r] += tr[r + st];
            l += tr[0] + swap_half(tr[0]);

            h8 pb[4];
#pragma unroll
            for (int kk = 0; kk < 4; ++kk) {
                const int bb = (kk & 1) * 8;
                unsigned W0, W1, W2, W3;
                if (kk < 2) {
                    W0 = __builtin_bit_cast(unsigned, __builtin_amdgcn_cvt_pkrtz(S0[bb + 0], S0[bb + 1]));
                    W1 = __builtin_bit_cast(unsigned, __builtin_amdgcn_cvt_pkrtz(S0[bb + 2], S0[bb + 3]));
                    W2 = __builtin_bit_cast(unsigned, __builtin_amdgcn_cvt_pkrtz(S0[bb + 4], S0[bb + 5]));
                    W3 = __builtin_bit_cast(unsigned, __builtin_amdgcn_cvt_pkrtz(S0[bb + 6], S0[bb + 7]));
                } else {
                    W0 = __builtin_bit_cast(unsigned, __builtin_amdgcn_cvt_pkrtz(S1[bb + 0], S1[bb + 1]));
                    W1 = __builtin_bit_cast(unsigned, __builtin_amdgcn_cvt_pkrtz(S1[bb + 2], S1[bb + 3]));
                    W2 = __builtin_bit_cast(unsigned, __builtin_amdgcn_cvt_pkrtz(S1[bb + 4], S1[bb + 5]));
                    W3 = __builtin_bit_cast(unsigned, __builtin_amdgcn_cvt_pkrtz(S1[bb + 6], S1[bb + 7]));
                }
                unsigned E0 = (unsigned)__shfl_xor((int)(hi ? W0 : W2), 32, 64);
                unsigned E1 = (unsigned)__shfl_xor((int)(hi ? W1 : W3), 32, 64);
                u4 wvv;
                wvv[0] = hi ? E0 : W0;
                wvv[1] = hi ? E1 : W1;
                wvv[2] = hi ? W2 : E0;
                wvv[3] = hi ? W3 : E1;
                pb[kk] = __builtin_bit_cast(h8, wvv);
            }

            __builtin_amdgcn_s_setprio(1);
#pragma unroll
            for (int kk = 0; kk < 4; ++kk) {
                h8 vf0 = *(const h8*)(&lds[4096 + SWZI(l31, kk * 32 + h16)]);
                h8 vf1 = *(const h8*)(&lds[4096 + SWZI(32 + l31, kk * 32 + h16)]);
                O0 = MFMA32(vf0, pb[kk], O0);
                O1 = MFMA32(vf1, pb[kk], O1);
            }
            __builtin_amdgcn_s_setprio(0);
        }

        __syncthreads();
        if (pre) {
#pragma unroll
            for (int j = 0; j < 2; ++j) {
                int row = j * 32 + sr;
                *(h8*)(&lds[SWZI(row, scb)]) = kn[j];
                *(h8*)(&lds[4096 + SWZI(row, scb)]) = vn[j];
            }
            __syncthreads();
        }
    }

    __syncthreads();

    {
        float inv = 1.0f / l;
        const int R = w * 32 + l31;
#pragma unroll
        for (int rr = 0; rr < 4; ++rr) {
            h4 a, b;
#pragma unroll
            for (int q = 0; q < 4; ++q) {
                a[q] = (_Float16)(O0[rr * 4 + q] * inv);
                b[q] = (_Float16)(O1[rr * 4 + q] * inv);
            }
            *(h4*)(&lds[SWZI(R, rr * 16 + hi * 8)]) = a;
            *(h4*)(&lds[SWZI(R, 64 + rr * 16 + hi * 8)]) = b;
        }
    }
    __syncthreads();
    {
        const int b = bh >> 4, head = bh & 15;
        const int row = tid >> 1;
#pragma unroll
        for (int i = 0; i < 4; ++i) {
            int seg = (tid & 1) * 4 + i;
            h8 v = *(const h8*)(&lds[SWZI(row, seg * 16)]);
            *(h8*)(Yh + ((size_t)(b * 2048 + qt * 128 + row)) * 1024 + head * 64 + seg * 8) = v;
        }
    }
}

extern "C" void kernel_launch(void* const* d_in, const int* in_sizes, int n_in,
                              void* d_out, int out_size, void* d_ws, size_t ws_size,
                              hipStream_t stream) {
    const float* x  = (const float*)d_in[0];
    const float* Wa = (const float*)d_in[1];
    const float* ba = (const float*)d_in[2];
    const float* Wp = (const float*)d_in[3];
    const float* bp = (const float*)d_in[4];
    float* out = (float*)d_out;

    _Float16* ws = (_Float16*)d_ws;
    const size_t SZ_WA = (size_t)3072 * 1024;
    const size_t SZ_WP = (size_t)1024 * 1024;
    const size_t SZ_H = (size_t)64 * 2048 * 64;
    _Float16* WaT = ws;
    _Float16* WpT = WaT + SZ_WA;
    _Float16* Qh  = WpT + SZ_WP;
    _Float16* Kh  = Qh + SZ_H;
    _Float16* Vth = Kh + SZ_H;    // V transposed: (bh, d, t)
    _Float16* Yh  = Vth + SZ_H;

    k_transpose_f16<<<dim3(16, 48), 256, 0, stream>>>(Wa, WaT, 1024, 3072);
    k_transpose_f16<<<dim3(16, 16), 256, 0, stream>>>(Wp, WpT, 1024, 1024);
    k_gemmQKV<<<dim3(64, 24), 256, 0, stream>>>(x, WaT, ba, Qh, Kh, Vth,
                                                8192, 3072, 1024);
    k_attn<<<1024, 256, 0, stream>>>(Qh, Kh, Vth, Yh);
    k_gemmP<<<dim3(64, 8), 256, 0, stream>>>(Yh, WpT, bp, out, 8192, 1024, 1024);
}